// Round 1
// baseline (2345.322 us; speedup 1.0000x reference)
//
#include <hip/hip_runtime.h>
#include <math.h>

#define B_   16
#define L_   8192
#define D_   64
#define R_   4
#define NB_  128   // n_buckets = L/64
#define NH_  64    // rand_matrix last dim = n_buckets/2

// ---------------- K1: normalize rand_matrix columns over d (fp64), store [b][r][n][d]
__global__ __launch_bounds__(64) void k_rmnorm(const float* __restrict__ rm, double* __restrict__ rmn) {
    int b = blockIdx.x >> 2, r = blockIdx.x & 3;
    int n = threadIdx.x;
    float v[D_];
    double ss = 0.0;
    #pragma unroll
    for (int d = 0; d < D_; ++d) {
        float f = rm[((size_t)(b * D_ + d) * R_ + r) * NH_ + n];
        v[d] = f;
        ss += (double)f * (double)f;
    }
    double nrm = sqrt(ss); if (nrm < 1e-12) nrm = 1e-12;
    double inv = 1.0 / nrm;
    double* o = rmn + ((size_t)(b * R_ + r) * NH_ + n) * D_;
    #pragma unroll
    for (int d = 0; d < D_; ++d) o[d] = (double)v[d] * inv;
}

// ---------------- K2: LSH hash, fp64 dots (argmax over [xR,-xR]); also 1/||q||
__global__ __launch_bounds__(256) void k_hash(const float* __restrict__ q, const double* __restrict__ rmn,
                                              float* __restrict__ rn, int* __restrict__ h) {
    __shared__ double rms[NH_ * D_]; // 32 KB
    int b = blockIdx.z, r = blockIdx.y;
    int l = blockIdx.x * 256 + threadIdx.x;
    const double* src = rmn + (size_t)(b * R_ + r) * NH_ * D_;
    for (int i = threadIdx.x; i < NH_ * D_; i += 256) rms[i] = src[i];
    const float* qp = q + ((size_t)b * L_ + l) * D_;
    double qd[D_];
    double ss = 0.0;
    #pragma unroll
    for (int d = 0; d < D_; d += 4) {
        float4 f = *(const float4*)(qp + d);
        qd[d] = f.x; qd[d+1] = f.y; qd[d+2] = f.z; qd[d+3] = f.w;
        ss += (double)f.x * f.x + (double)f.y * f.y + (double)f.z * f.z + (double)f.w * f.w;
    }
    __syncthreads();
    double best = -1.0e300; int bi = 0;
    for (int n = 0; n < NH_; ++n) {
        const double* kp = &rms[n * D_];
        double a0 = 0, a1 = 0, a2 = 0, a3 = 0;
        #pragma unroll
        for (int d = 0; d < D_; d += 4) {
            a0 = fma(qd[d],   kp[d],   a0);
            a1 = fma(qd[d+1], kp[d+1], a1);
            a2 = fma(qd[d+2], kp[d+2], a2);
            a3 = fma(qd[d+3], kp[d+3], a3);
        }
        double s = (a0 + a1) + (a2 + a3);
        if (s > best)  { best = s;  bi = n; }        // +xR first (ref concat order)
        if (-s > best) { best = -s; bi = n + NH_; }  // then -xR
    }
    h[(size_t)(b * R_ + r) * L_ + l] = bi;
    if (r == 0) {
        double nrm = sqrt(ss); if (nrm < 1e-12) nrm = 1e-12;
        rn[(size_t)b * L_ + l] = (float)(1.0 / nrm);
    }
}

// ---------------- K3: stable counting sort by bucket per (b,r); 1 wave per block
__global__ __launch_bounds__(64) void k_sort(const int* __restrict__ h, int* __restrict__ idx,
                                             int* __restrict__ sb) {
    __shared__ unsigned int cnt[NB_ * 64]; // [bucket][thread], 32 KB
    int br = blockIdx.x;
    const int* hh = h + (size_t)br * L_;
    int t = threadIdx.x;
    for (int i = t; i < NB_ * 64; i += 64) cnt[i] = 0;
    __syncthreads();
    int base = t * 128;                      // each thread owns 128 consecutive l
    for (int i = 0; i < 128; ++i) { int bk = hh[base + i]; cnt[bk * 64 + t]++; }
    __syncthreads();
    // exclusive prefix over flattened [bucket*64 + thread]; thread t owns buckets 2t,2t+1
    int fb = t * 128;
    unsigned int local = 0;
    for (int i = 0; i < 128; ++i) local += cnt[fb + i];
    unsigned int v = local;
    #pragma unroll
    for (int off = 1; off < 64; off <<= 1) {
        unsigned int u = __shfl_up(v, off);
        if (t >= off) v += u;
    }
    unsigned int run = v - local; // exclusive base for this thread's 128 cells
    for (int i = 0; i < 128; ++i) { unsigned int c0 = cnt[fb + i]; cnt[fb + i] = run; run += c0; }
    __syncthreads();
    int* oi = idx + (size_t)br * L_;
    int* ob = sb  + (size_t)br * L_;
    for (int i = 0; i < 128; ++i) {
        int l = base + i; int bk = hh[l];
        unsigned int pos = cnt[bk * 64 + t]++;
        oi[pos] = l; ob[pos] = bk;
    }
}

// ---------------- K4: pass 1 — lse per sorted position. 1 wave = 64 queries of a chunk.
__global__ __launch_bounds__(64) void k_lse(const float* __restrict__ q, const int* __restrict__ idx,
                                            const int* __restrict__ sb, const float* __restrict__ rn,
                                            float* __restrict__ lse) {
    __shared__ float kt[32 * 68];  // 32 key rows, padded stride 68
    __shared__ int   kq[32];
    __shared__ int   kb[32];
    __shared__ float kr[32];
    int c = blockIdx.x, r = blockIdx.y, b = blockIdx.z;
    size_t sbase = (size_t)(b * R_ + r) * L_;
    int lane = threadIdx.x;
    int pos = c * 64 + lane;
    int myl = idx[sbase + pos];
    int mybk = sb[sbase + pos];
    const float* qb = q + (size_t)b * L_ * D_;
    float qv[D_];
    {
        const float* qp = qb + (size_t)myl * D_;
        #pragma unroll
        for (int d = 0; d < D_; d += 4) {
            float4 f = *(const float4*)(qp + d);
            qv[d] = f.x; qv[d+1] = f.y; qv[d+2] = f.z; qv[d+3] = f.w;
        }
    }
    float m = -3.0e38f, sum = 0.0f;
    for (int s = 0; s < 4; ++s) {  // 4 stages of 32 keys: prev chunk then current chunk
        int cbase = ((c + NB_ - 1 + (s >> 1)) % NB_) * 64 + (s & 1) * 32;
        __syncthreads();
        int rw = lane >> 1, hf = lane & 1;
        int kl = idx[sbase + cbase + rw];
        const float* kp = qb + (size_t)kl * D_ + hf * 32;
        float* kd = &kt[rw * 68 + hf * 32];
        #pragma unroll
        for (int i = 0; i < 32; i += 4) *(float4*)(kd + i) = *(const float4*)(kp + i);
        if (lane < 32) {
            int kl2 = idx[sbase + cbase + lane];
            kq[lane] = kl2;
            kb[lane] = sb[sbase + cbase + lane];
            kr[lane] = rn[(size_t)b * L_ + kl2];
        }
        __syncthreads();
        for (int j = 0; j < 32; ++j) {
            const float* kpj = &kt[j * 68];
            float a0 = 0, a1 = 0, a2 = 0, a3 = 0;
            #pragma unroll
            for (int d = 0; d < D_; d += 4) {
                float4 kk = *(const float4*)(kpj + d);   // broadcast ds_read_b128
                a0 = fmaf(qv[d],   kk.x, a0); a1 = fmaf(qv[d+1], kk.y, a1);
                a2 = fmaf(qv[d+2], kk.z, a2); a3 = fmaf(qv[d+3], kk.w, a3);
            }
            float sc = ((a0 + a1) + (a2 + a3)) * kr[j] * 0.125f;
            sc = (kb[j] == mybk) ? sc : -1.0e9f;   // cross-bucket mask
            if (kq[j] == myl) sc = -1.0e5f;        // self mask (overrides, as in ref)
            // online logsumexp, exactly one expf per key
            float nm = fmaxf(m, sc);
            float e  = expf(fminf(sc, m) - nm);
            sum = (sc > m) ? fmaf(sum, e, 1.0f) : (sum + e);
            m = nm;
        }
    }
    lse[sbase + pos] = m + logf(sum);
}

// ---------------- K5: softmax-over-L normalizers (max + fp64 sum) per (b,r)
__global__ __launch_bounds__(256) void k_wred(const float* __restrict__ lse, float* __restrict__ gm,
                                              float* __restrict__ gs) {
    __shared__ float  sm[4];
    __shared__ double sd[4];
    int br = blockIdx.x;
    const float* x = lse + (size_t)br * L_;
    int t = threadIdx.x;
    float mx = -3.0e38f;
    for (int i = t; i < L_; i += 256) mx = fmaxf(mx, x[i]);
    #pragma unroll
    for (int o = 32; o; o >>= 1) mx = fmaxf(mx, __shfl_down(mx, o));
    if ((t & 63) == 0) sm[t >> 6] = mx;
    __syncthreads();
    mx = fmaxf(fmaxf(sm[0], sm[1]), fmaxf(sm[2], sm[3]));
    double s = 0.0;
    for (int i = t; i < L_; i += 256) s += exp((double)x[i] - (double)mx);
    #pragma unroll
    for (int o = 32; o; o >>= 1) s += __shfl_down(s, o);
    if ((t & 63) == 0) sd[t >> 6] = s;
    __syncthreads();
    if (t == 0) { gm[br] = mx; gs[br] = (float)(1.0 / (sd[0] + sd[1] + sd[2] + sd[3])); }
}

// ---------------- K6: pass 2 — recompute scores, p·V, scale by w, atomic accumulate
__global__ __launch_bounds__(64) void k_att(const float* __restrict__ q, const float* __restrict__ val,
                                            const int* __restrict__ idx, const int* __restrict__ sb,
                                            const float* __restrict__ rn, const float* __restrict__ lse,
                                            const float* __restrict__ gm, const float* __restrict__ gs,
                                            float* __restrict__ out) {
    __shared__ float kt[32 * 68];
    __shared__ float vt[32 * 68];
    __shared__ int   kq[32];
    __shared__ int   kb[32];
    __shared__ float kr[32];
    int c = blockIdx.x, r = blockIdx.y, b = blockIdx.z;
    size_t sbase = (size_t)(b * R_ + r) * L_;
    int lane = threadIdx.x;
    int pos = c * 64 + lane;
    int myl = idx[sbase + pos];
    int mybk = sb[sbase + pos];
    const float* qb = q   + (size_t)b * L_ * D_;
    const float* vb = val + (size_t)b * L_ * D_;
    float qv[D_];
    {
        const float* qp = qb + (size_t)myl * D_;
        #pragma unroll
        for (int d = 0; d < D_; d += 4) {
            float4 f = *(const float4*)(qp + d);
            qv[d] = f.x; qv[d+1] = f.y; qv[d+2] = f.z; qv[d+3] = f.w;
        }
    }
    float myLse = lse[sbase + pos];
    float acc[D_];
    #pragma unroll
    for (int d = 0; d < D_; ++d) acc[d] = 0.0f;
    for (int s = 0; s < 4; ++s) {
        int cbase = ((c + NB_ - 1 + (s >> 1)) % NB_) * 64 + (s & 1) * 32;
        __syncthreads();
        int rw = lane >> 1, hf = lane & 1;
        int kl = idx[sbase + cbase + rw];
        const float* kp = qb + (size_t)kl * D_ + hf * 32;
        const float* vp = vb + (size_t)kl * D_ + hf * 32;
        float* kd = &kt[rw * 68 + hf * 32];
        float* vd = &vt[rw * 68 + hf * 32];
        #pragma unroll
        for (int i = 0; i < 32; i += 4) {
            *(float4*)(kd + i) = *(const float4*)(kp + i);
            *(float4*)(vd + i) = *(const float4*)(vp + i);
        }
        if (lane < 32) {
            int kl2 = idx[sbase + cbase + lane];
            kq[lane] = kl2;
            kb[lane] = sb[sbase + cbase + lane];
            kr[lane] = rn[(size_t)b * L_ + kl2];
        }
        __syncthreads();
        for (int j = 0; j < 32; ++j) {
            const float* kpj = &kt[j * 68];
            float a0 = 0, a1 = 0, a2 = 0, a3 = 0;
            #pragma unroll
            for (int d = 0; d < D_; d += 4) {
                float4 kk = *(const float4*)(kpj + d);
                a0 = fmaf(qv[d],   kk.x, a0); a1 = fmaf(qv[d+1], kk.y, a1);
                a2 = fmaf(qv[d+2], kk.z, a2); a3 = fmaf(qv[d+3], kk.w, a3);
            }
            float sc = ((a0 + a1) + (a2 + a3)) * kr[j] * 0.125f;
            sc = (kb[j] == mybk) ? sc : -1.0e9f;
            if (kq[j] == myl) sc = -1.0e5f;
            float p = expf(sc - myLse);           // masked keys underflow to 0, as in ref
            const float* vpj = &vt[j * 68];
            #pragma unroll
            for (int d = 0; d < D_; d += 4) {
                float4 vv = *(const float4*)(vpj + d);
                acc[d]   = fmaf(p, vv.x, acc[d]);   acc[d+1] = fmaf(p, vv.y, acc[d+1]);
                acc[d+2] = fmaf(p, vv.z, acc[d+2]); acc[d+3] = fmaf(p, vv.w, acc[d+3]);
            }
        }
    }
    int brr = b * R_ + r;
    float w = expf(myLse - gm[brr]) * gs[brr];
    float* op = out + ((size_t)b * L_ + myl) * D_;
    #pragma unroll
    for (int d = 0; d < D_; ++d) unsafeAtomicAdd(op + d, w * acc[d]);
}

// ---------------- workspace layout (bytes), total ~10.5 MB
#define OFF_RMN 0u
#define OFF_RN  2097152u
#define OFF_H   2621440u
#define OFF_IDX 4718592u
#define OFF_SB  6815744u
#define OFF_LSE 8912896u
#define OFF_GM  11010048u
#define OFF_GS  11010304u

extern "C" void kernel_launch(void* const* d_in, const int* in_sizes, int n_in,
                              void* d_out, int out_size, void* d_ws, size_t ws_size,
                              hipStream_t stream) {
    const float* q  = (const float*)d_in[0];
    const float* v  = (const float*)d_in[1];
    const float* rm = (const float*)d_in[2];
    float* out = (float*)d_out;
    char* ws = (char*)d_ws;
    double* rmn = (double*)(ws + OFF_RMN);
    float*  rn  = (float*)(ws + OFF_RN);
    int*    h   = (int*)(ws + OFF_H);
    int*    idx = (int*)(ws + OFF_IDX);
    int*    sb  = (int*)(ws + OFF_SB);
    float*  lse = (float*)(ws + OFF_LSE);
    float*  gm  = (float*)(ws + OFF_GM);
    float*  gs  = (float*)(ws + OFF_GS);

    hipMemsetAsync(d_out, 0, (size_t)B_ * L_ * D_ * sizeof(float), stream);
    hipLaunchKernelGGL(k_rmnorm, dim3(B_ * R_), dim3(64), 0, stream, rm, rmn);
    hipLaunchKernelGGL(k_hash, dim3(L_ / 256, R_, B_), dim3(256), 0, stream, q, rmn, rn, h);
    hipLaunchKernelGGL(k_sort, dim3(B_ * R_), dim3(64), 0, stream, h, idx, sb);
    hipLaunchKernelGGL(k_lse, dim3(NB_, R_, B_), dim3(64), 0, stream, q, idx, sb, rn, lse);
    hipLaunchKernelGGL(k_wred, dim3(B_ * R_), dim3(256), 0, stream, lse, gm, gs);
    hipLaunchKernelGGL(k_att, dim3(NB_, R_, B_), dim3(64), 0, stream, q, v, idx, sb, rn, lse, gm, gs, out);
}